// Round 4
// baseline (1563.612 us; speedup 1.0000x reference)
//
#include <hip/hip_runtime.h>
#include <hip/hip_bf16.h>
#include <stdint.h>

typedef __hip_bfloat16 bf16;
typedef unsigned short u16;
typedef unsigned int u32;
typedef __bf16 v8bf __attribute__((ext_vector_type(8)));
typedef float v4f __attribute__((ext_vector_type(4)));

// Problem constants
#define NB 16384            // B
#define MROWS 147456        // T*B*3 token rows

// Counted-wait / barrier primitives (T3+T4 recipe, m201 pattern)
#define VMWAIT4 do { asm volatile("s_waitcnt vmcnt(4)" ::: "memory"); } while (0)
#define VMWAIT0 do { asm volatile("s_waitcnt vmcnt(0)" ::: "memory"); } while (0)
#define LGKM0   do { asm volatile("s_waitcnt lgkmcnt(0)" ::: "memory"); } while (0)
#define SCHEDB  __builtin_amdgcn_sched_barrier(0)
#define SBAR    __builtin_amdgcn_s_barrier()

__device__ __forceinline__ float b2f(u16 u) {
  union { u32 u; float f; } v; v.u = ((u32)u) << 16; return v.f;
}
__device__ __forceinline__ u16 f2b(float f) {
  union { float f; u32 u; } v; v.f = f;
  u32 u = v.u;
  return (u16)((u + 0x7fffu + ((u >> 16) & 1u)) >> 16);
}
__device__ __forceinline__ void async16(const u16* g, u16* lds) {
  __builtin_amdgcn_global_load_lds((const __attribute__((address_space(1))) void*)g,
                                   (__attribute__((address_space(3))) void*)lds,
                                   16, 0, 0);
}
__device__ __forceinline__ v4f mfma16(v8bf a, v8bf b, v4f c) {
  return __builtin_amdgcn_mfma_f32_16x16x32_bf16(a, b, c, 0, 0, 0);
}

// ---- swizzled LDS reads -----------------------------------------------------
// As: [64][256] bf16 (512 B rows), XOR (row&7)<<4 -> conflict-free b128
__device__ __forceinline__ v8bf ldsA256(const u16* As, int row, int k) {
  int byte = (row << 9) + ((k << 1) ^ ((row & 7) << 4));
  return *(const v8bf*)((const char*)As + byte);
}
// Fs: [64][128] bf16 (256 B rows), XOR (row&7)<<4
__device__ __forceinline__ v8bf ldsF128(const u16* Fs, int row, int k) {
  int byte = (row << 8) + ((k << 1) ^ ((row & 7) << 4));
  return *(const v8bf*)((const char*)Fs + byte);
}
// B tile [128 rows][64 k] (128 B rows), XOR (row&7)<<4; kb = in-row byte
__device__ __forceinline__ v8bf ldsB64(const u16* Bs, int row, int kb) {
  int byte = (row << 7) + (kb ^ ((row & 7) << 4));
  return *(const v8bf*)((const char*)Bs + byte);
}
// B tile [256 rows][32 k] (64 B rows), XOR ((row>>1)&3)<<4
__device__ __forceinline__ v8bf ldsB32(const u16* Bs, int row, int kb) {
  int byte = (row << 6) + (kb ^ (((row >> 1) & 3) << 4));
  return *(const v8bf*)((const char*)Bs + byte);
}

// ---- 16 KB B-tile staging via global_load_lds (linear LDS dest, pre-swizzled
// global source). 256 threads x 4 async16. S = global row stride (elements).
__device__ __forceinline__ void soB32_init(int tid, int S, int* so) {
  #pragma unroll
  for (int i = 0; i < 4; i++) {
    int b = tid * 16 + i * 4096;       // linear LDS byte in [0,16384)
    int r = b >> 6, ib = b & 63;       // [256][32] tile, 64 B rows
    so[i] = r * S + ((ib ^ (((r >> 1) & 3) << 4)) >> 1);
  }
}
__device__ __forceinline__ void soB64_init(int tid, int S, int* so) {
  #pragma unroll
  for (int i = 0; i < 4; i++) {
    int b = tid * 16 + i * 4096;       // [128][64] tile, 128 B rows
    int r = b >> 7, ib = b & 127;
    so[i] = r * S + ((ib ^ ((r & 7) << 4)) >> 1);
  }
}
__device__ __forceinline__ void stageB(const u16* g, const int* so, u16* dst, int tid) {
  #pragma unroll
  for (int i = 0; i < 4; i++)
    async16(g + so[i], dst + tid * 8 + i * 2048);
}

// ---------------------------------------------------------------------------
// Weight prep (unchanged): transposed bf16 [N][K] per-layer layout in wt:
// q 0, k 65536, v 131072, o 196608, W1T 262144 (1024x256),
// W2T 524288 (256x1024); layer stride 786432 elements. bqkv: [l][qkv][256] f32.
// ---------------------------------------------------------------------------
__global__ __launch_bounds__(256)
void prep_weights(const float* Wq, const float* Wk, const float* Wv, const float* Wo,
                  const float* W1, const float* W2,
                  const float* bq, const float* bk, const float* bv,
                  bf16* wt, float* bqkv)
{
  if (blockIdx.x == 6144) {   // bias-pack block
    for (int e = threadIdx.x; e < 1536; e += 256) {
      int l = e / 768;
      int rem = e - l * 768;
      int wsel = rem >> 8;
      int col = rem & 255;
      const float* s = (wsel == 0) ? bq : (wsel == 1) ? bk : bv;
      bqkv[e] = s[l * 256 + col];
    }
    return;
  }
  int gid = blockIdx.x * 256 + threadIdx.x;   // [0, 1572864)
  int layer = (gid >= 786432) ? 1 : 0;
  int r = gid - layer * 786432;
  const float* src; int K, N, e, outoff;
  if (r < 262144) {
    int which = r >> 16;
    e = r & 65535; K = 256; N = 256;
    const float* w = (which == 0) ? Wq : (which == 1) ? Wk : (which == 2) ? Wv : Wo;
    src = w + layer * 65536;
    outoff = layer * 786432 + which * 65536;
  } else if (r < 524288) {
    e = r - 262144; K = 256; N = 1024;
    src = W1 + layer * 262144;
    outoff = layer * 786432 + 262144;
  } else {
    e = r - 524288; K = 1024; N = 256;
    src = W2 + layer * 262144;
    outoff = layer * 786432 + 524288;
  }
  int n = e / K, kk = e - n * K;
  ((u16*)wt)[outoff + e] = f2b(src[kk * N + n]);
}

// ---------------------------------------------------------------------------
// Graph-message build: write x rows (f32). 1 wave per row, 4 rows per block.
// ---------------------------------------------------------------------------
__global__ __launch_bounds__(256)
void build_x(const float* __restrict__ T, const float* __restrict__ P,
             float* __restrict__ X, int row0)
{
  const int lane = threadIdx.x & 63;
  const int lrow = blockIdx.x * 4 + (threadIdx.x >> 6);
  const int row = row0 + lrow;
  const int d0 = lane * 4;
  int n = row / 3;
  int t = row - n * 3;
  float4 v;
  if (t == 2) {
    v = *(const float4*)(T + (size_t)n * 256 + d0);
  } else {
    int tm = n >> 14, b = n & 16383;
    const int srcT[6] = {1, 2,  0, 2,  1, 0};
    const int srcP[6] = {0, 2,  0, 1,  1, 2};
    const float sg[6] = {-1.f, -1.f,  1.f, -1.f,  1.f, 1.f};
    int idx = tm * 2 + t;
    float4 tv = *(const float4*)(T + ((size_t)(srcT[idx] * NB + b)) * 256 + d0);
    float4 pv = *(const float4*)(P + ((size_t)(srcP[idx] * NB + b)) * 256 + d0);
    float s = sg[idx];
    v.x = tv.x + s * pv.x;
    v.y = tv.y + s * pv.y;
    v.z = tv.z + s * pv.z;
    v.w = tv.w + s * pv.w;
  }
  *(float4*)(X + (size_t)lrow * 256 + d0) = v;
}

// ---------------------------------------------------------------------------
// LN stage: 64 rows of x (f32) -> LayerNorm -> bf16 swizzled LDS As[64][256].
// 4 waves; wave w handles rows {w, w+4, ..., w+60}. Coalesced 1 KB row reads.
// ---------------------------------------------------------------------------
__device__ __forceinline__ void ln_stage(const float* __restrict__ xp,
                                         const float* __restrict__ gp,
                                         const float* __restrict__ bp,
                                         u16* As, int m0, int w, int lane)
{
  const float4 gv = *(const float4*)(gp + lane * 4);
  const float4 bv = *(const float4*)(bp + lane * 4);
  for (int r = w; r < 64; r += 4) {
    float4 v = *(const float4*)(xp + (size_t)(m0 + r) * 256 + lane * 4);
    float s = v.x + v.y + v.z + v.w;
    float q = v.x * v.x + v.y * v.y + v.z * v.z + v.w * v.w;
    #pragma unroll
    for (int m = 32; m > 0; m >>= 1) {
      s += __shfl_xor(s, m, 64);
      q += __shfl_xor(q, m, 64);
    }
    float mean = s * (1.f / 256.f);
    float var = q * (1.f / 256.f) - mean * mean;
    float rr = rsqrtf(var + 1e-5f);
    ushort4 o;
    o.x = f2b((v.x - mean) * rr * gv.x + bv.x);
    o.y = f2b((v.y - mean) * rr * gv.y + bv.y);
    o.z = f2b((v.z - mean) * rr * gv.z + bv.z);
    o.w = f2b((v.w - mean) * rr * gv.w + bv.w);
    int byte = (r << 9) + ((lane << 3) ^ ((r & 7) << 4));
    *(ushort4*)((char*)As + byte) = o;
  }
}

// ---------------------------------------------------------------------------
// Fused LN1 + QKV. 64-row tile, 4 waves (256 thr). Each wave: all 64 rows x a
// 64-col strip -> per 32-k step: 4 A-reads + 4 B-reads feed 16 MFMAs (R=4).
// B pipelined as 24 [256][32] tiles through a 2x16 KB buffer with counted
// vmcnt(4) + raw barriers (no drain-0 in the loop). LDS 64 KB -> 2 blocks/CU.
// ---------------------------------------------------------------------------
__global__ __launch_bounds__(256, 2)
void qkv_fused(const float* __restrict__ xp, const float* __restrict__ gp,
               const float* __restrict__ bp, const bf16* __restrict__ wp,
               const float* __restrict__ biasp, bf16* __restrict__ qkv,
               long long qkvZ)
{
  __shared__ __align__(16) u16 As[64 * 256];    // 32 KB
  __shared__ __align__(16) u16 Bs[2 * 8192];    // 32 KB (16 KB per buffer)
  const int tid = threadIdx.x;
  const int w = tid >> 6, lane = tid & 63;
  const int m0 = blockIdx.x * 64;
  const int fl = lane & 15, fh = lane >> 4;
  const int wc = w * 64;
  int so[4];
  soB32_init(tid, 256, so);
  const u16* wp16 = (const u16*)wp;
  stageB(wp16, so, Bs, tid);                    // tile 0 (wsel 0, ks 0)
  ln_stage(xp, gp, bp, As, m0, w, lane);
  __syncthreads();                              // full drain: As + tile0 ready
  #pragma unroll 1
  for (int wsel = 0; wsel < 3; wsel++) {
    v4f acc[4][4];
    #pragma unroll
    for (int mi = 0; mi < 4; mi++)
      #pragma unroll
      for (int nj = 0; nj < 4; nj++) { v4f z = {0.f,0.f,0.f,0.f}; acc[mi][nj] = z; }
    #pragma unroll
    for (int ks = 0; ks < 8; ks++) {
      u16* nbuf = Bs + (((ks + 1) & 1) * 8192);
      if (ks < 7) {
        stageB(wp16 + wsel * 65536 + (ks + 1) * 32, so, nbuf, tid);
        VMWAIT4;
      } else if (wsel < 2) {
        stageB(wp16 + (wsel + 1) * 65536, so, nbuf, tid);
        VMWAIT4;
      } else {
        VMWAIT0;
      }
      SCHEDB; SBAR; SCHEDB;
      const u16* Bt = Bs + (ks & 1) * 8192;
      v8bf a0 = ldsA256(As, 0 * 16 + fl, ks * 32 + fh * 8);
      v8bf a1 = ldsA256(As, 1 * 16 + fl, ks * 32 + fh * 8);
      v8bf a2 = ldsA256(As, 2 * 16 + fl, ks * 32 + fh * 8);
      v8bf a3 = ldsA256(As, 3 * 16 + fl, ks * 32 + fh * 8);
      #pragma unroll
      for (int nj = 0; nj < 4; nj++) {
        v8bf b = ldsB32(Bt, wc + nj * 16 + fl, fh * 16);
        acc[0][nj] = mfma16(a0, b, acc[0][nj]);
        acc[1][nj] = mfma16(a1, b, acc[1][nj]);
        acc[2][nj] = mfma16(a2, b, acc[2][nj]);
        acc[3][nj] = mfma16(a3, b, acc[3][nj]);
      }
      SCHEDB; SBAR;                              // all reads of Bt retired
    }
    u16* out = (u16*)qkv + (size_t)wsel * qkvZ;
    #pragma unroll
    for (int nj = 0; nj < 4; nj++) {
      const int col = wc + nj * 16 + fl;
      const float bb = biasp[wsel * 256 + col];
      #pragma unroll
      for (int mi = 0; mi < 4; mi++)
        #pragma unroll
        for (int r2 = 0; r2 < 4; r2++) {
          int row = m0 + mi * 16 + fh * 4 + r2;
          out[(size_t)row * 256 + col] = f2b(acc[mi][nj][r2] + bb);
        }
    }
  }
}

// ---------------------------------------------------------------------------
// O-projection: x += o @ WoT + bo. A staged via pre-swizzled-source async16;
// Wo pipelined as 8 [256][32] tiles, counted vmcnt. LDS 64 KB -> 2 blocks/CU.
// ---------------------------------------------------------------------------
__global__ __launch_bounds__(256, 2)
void oproj(const bf16* __restrict__ op, const bf16* __restrict__ wop,
           const float* __restrict__ bop, float* __restrict__ xp)
{
  __shared__ __align__(16) u16 As[64 * 256];    // 32 KB
  __shared__ __align__(16) u16 Bs[2 * 8192];    // 32 KB
  const int tid = threadIdx.x;
  const int w = tid >> 6, lane = tid & 63;
  const int m0 = blockIdx.x * 64;
  const int fl = lane & 15, fh = lane >> 4;
  const int wc = w * 64;
  const u16* og = (const u16*)op + (size_t)m0 * 256;
  #pragma unroll
  for (int i = 0; i < 8; i++) {
    int b = tid * 16 + i * 4096;                 // linear LDS byte [0,32768)
    int row = b >> 9, cb = b & 511;
    int srce = row * 256 + ((cb ^ ((row & 7) << 4)) >> 1);
    async16(og + srce, As + (b >> 1));
  }
  int so[4];
  soB32_init(tid, 256, so);
  const u16* wo16 = (const u16*)wop;
  stageB(wo16, so, Bs, tid);
  __syncthreads();                               // drain: As + tile0
  v4f acc[4][4];
  #pragma unroll
  for (int mi = 0; mi < 4; mi++)
    #pragma unroll
    for (int nj = 0; nj < 4; nj++) { v4f z = {0.f,0.f,0.f,0.f}; acc[mi][nj] = z; }
  #pragma unroll
  for (int ks = 0; ks < 8; ks++) {
    if (ks < 7) {
      stageB(wo16 + (ks + 1) * 32, so, Bs + (((ks + 1) & 1) * 8192), tid);
      VMWAIT4;
    } else {
      VMWAIT0;
    }
    SCHEDB; SBAR; SCHEDB;
    const u16* Bt = Bs + (ks & 1) * 8192;
    v8bf a0 = ldsA256(As, 0 * 16 + fl, ks * 32 + fh * 8);
    v8bf a1 = ldsA256(As, 1 * 16 + fl, ks * 32 + fh * 8);
    v8bf a2 = ldsA256(As, 2 * 16 + fl, ks * 32 + fh * 8);
    v8bf a3 = ldsA256(As, 3 * 16 + fl, ks * 32 + fh * 8);
    #pragma unroll
    for (int nj = 0; nj < 4; nj++) {
      v8bf b = ldsB32(Bt, wc + nj * 16 + fl, fh * 16);
      acc[0][nj] = mfma16(a0, b, acc[0][nj]);
      acc[1][nj] = mfma16(a1, b, acc[1][nj]);
      acc[2][nj] = mfma16(a2, b, acc[2][nj]);
      acc[3][nj] = mfma16(a3, b, acc[3][nj]);
    }
    SCHEDB; SBAR;
  }
  #pragma unroll
  for (int nj = 0; nj < 4; nj++) {
    const int col = wc + nj * 16 + fl;
    const float bb = bop[col];
    #pragma unroll
    for (int mi = 0; mi < 4; mi++)
      #pragma unroll
      for (int r2 = 0; r2 < 4; r2++) {
        size_t idx = (size_t)(m0 + mi * 16 + fh * 4 + r2) * 256 + col;
        xp[idx] += acc[mi][nj][r2] + bb;
      }
  }
}

// ---------------------------------------------------------------------------
// Fused FFN: x += relu(LN2(x) @ W1 + b1) @ W2 + b2. 64-row tile, 4 waves.
// 8 chunks of 128 hidden cols. Per chunk: 4 W1 steps ([128][64] tiles,
// 6 reads/8 MFMA per wave) -> bias+relu -> swizzled Fs[64][128] -> 4 W2 steps
// ([256][32] tiles, 8 reads/16 MFMA) into persistent acc. Counted vmcnt,
// 2 raw barriers/step. LDS 80 KB -> 2 blocks/CU. f never touches HBM.
// ---------------------------------------------------------------------------
__global__ __launch_bounds__(256, 2)
void ffn_fused(float* __restrict__ xp, const float* __restrict__ gp,
               const float* __restrict__ bp, const bf16* __restrict__ w1p,
               const bf16* __restrict__ w2p, const float* __restrict__ b1p,
               const float* __restrict__ b2p)
{
  __shared__ __align__(16) u16 As[64 * 256];    // 32 KB
  __shared__ __align__(16) u16 Fs[64 * 128];    // 16 KB
  __shared__ __align__(16) u16 Bs[2 * 8192];    // 32 KB
  const int tid = threadIdx.x;
  const int w = tid >> 6, lane = tid & 63;
  const int m0 = blockIdx.x * 64;
  const int fl = lane & 15, fh = lane >> 4;
  const int wc1 = w * 32;                       // W1 strip within 128 cols
  const int wc2 = w * 64;                       // W2 strip within 256 cols
  int so1[4], so2[4];
  soB64_init(tid, 256, so1);
  soB32_init(tid, 1024, so2);
  const u16* w1 = (const u16*)w1p;
  const u16* w2 = (const u16*)w2p;
  stageB(w1, so1, Bs, tid);                     // nc=0, W1 ks=0
  ln_stage(xp, gp, bp, As, m0, w, lane);
  __syncthreads();                              // drain: As + tile0
  v4f acc[4][4];
  #pragma unroll
  for (int mi = 0; mi < 4; mi++)
    #pragma unroll
    for (int nj = 0; nj < 4; nj++) { v4f z = {0.f,0.f,0.f,0.f}; acc[mi][nj] = z; }
  #pragma unroll 1
  for (int nc = 0; nc < 8; nc++) {
    v4f fa[4][2];
    #pragma unroll
    for (int mi = 0; mi < 4; mi++)
      #pragma unroll
      for (int nj = 0; nj < 2; nj++) { v4f z = {0.f,0.f,0.f,0.f}; fa[mi][nj] = z; }
    #pragma unroll
    for (int sub = 0; sub < 8; sub++) {
      u16* nbuf = Bs + (((sub + 1) & 1) * 8192);
      if (sub < 3) {                            // next is W1 tile ks=sub+1
        stageB(w1 + nc * 32768 + (sub + 1) * 64, so1, nbuf, tid);
        VMWAIT4;
      } else if (sub < 7) {                     // next is W2 tile ks=sub-3
        stageB(w2 + nc * 128 + (sub - 3) * 32, so2, nbuf, tid);
        VMWAIT4;
      } else if (nc < 7) {                      // next chunk's W1 ks=0
        stageB(w1 + (nc + 1) * 32768, so1, nbuf, tid);
        VMWAIT4;
      } else {
        VMWAIT0;
      }
      SCHEDB; SBAR; SCHEDB;
      const u16* Bt = Bs + (sub & 1) * 8192;
      if (sub < 4) {
        // ---- W1 step: fa += A[:, sub*64..] @ W1tile ----
        #pragma unroll
        for (int kl = 0; kl < 2; kl++) {
          const int kA = sub * 64 + kl * 32 + fh * 8;
          v8bf a0 = ldsA256(As, 0 * 16 + fl, kA);
          v8bf a1 = ldsA256(As, 1 * 16 + fl, kA);
          v8bf a2 = ldsA256(As, 2 * 16 + fl, kA);
          v8bf a3 = ldsA256(As, 3 * 16 + fl, kA);
          v8bf b0 = ldsB64(Bt, wc1 + fl, kl * 64 + fh * 16);
          v8bf b1 = ldsB64(Bt, wc1 + 16 + fl, kl * 64 + fh * 16);
          fa[0][0] = mfma16(a0, b0, fa[0][0]);
          fa[1][0] = mfma16(a1, b0, fa[1][0]);
          fa[2][0] = mfma16(a2, b0, fa[2][0]);
          fa[3][0] = mfma16(a3, b0, fa[3][0]);
          fa[0][1] = mfma16(a0, b1, fa[0][1]);
          fa[1][1] = mfma16(a1, b1, fa[1][1]);
          fa[2][1] = mfma16(a2, b1, fa[2][1]);
          fa[3][1] = mfma16(a3, b1, fa[3][1]);
        }
        if (sub == 3) {
          // bias + relu -> swizzled Fs (chunk-local cols 0..127)
          #pragma unroll
          for (int nj = 0; nj < 2; nj++) {
            const int colc = wc1 + nj * 16 + fl;
            const float bb = b1p[nc * 128 + colc];
            #pragma unroll
            for (int mi = 0; mi < 4; mi++)
              #pragma unroll
              for (int r2 = 0; r2 < 4; r2++) {
                int row = mi * 16 + fh * 4 + r2;
                float vv = fmaxf(fa[mi][nj][r2] + bb, 0.f);
                int byte = (row << 8) + (((colc << 1)) ^ ((row & 7) << 4));
                *(u16*)((char*)Fs + byte) = f2b(vv);
              }
          }
          LGKM0; SCHEDB;                        // Fs writes complete
        }
      } else {
        // ---- W2 step: acc += Fs[:, ks*32..] @ W2tile ----
        const int ks = sub - 4;
        v8bf f0 = ldsF128(Fs, 0 * 16 + fl, ks * 32 + fh * 8);
        v8bf f1 = ldsF128(Fs, 1 * 16 + fl, ks * 32 + fh * 8);
        v8bf f2 = ldsF128(Fs, 2 * 16 + fl, ks * 32 + fh * 8);
        v8bf f3 = ldsF128(Fs, 3 * 16 + fl, ks * 32 + fh * 8);
        #pragma unroll
        for (int nj = 0; nj < 4; nj++) {
          v8bf b = ldsB32(Bt, wc2 + nj * 16 + fl, fh * 16);
          acc[0][nj] = mfma16(f0, b, acc[0][nj]);
          acc[1][nj] = mfma16(f1, b, acc[1][nj]);
          acc[2][nj] = mfma16(f2, b, acc[2][nj]);
          acc[3][nj] = mfma16(f3, b, acc[3][nj]);
        }
      }
      SCHEDB; SBAR;                              // all reads of Bt/Fs retired
    }
  }
  // epilogue: + b2 + residual, write x (f32)
  #pragma unroll
  for (int nj = 0; nj < 4; nj++) {
    const int col = wc2 + nj * 16 + fl;
    const float bb = b2p[col];
    #pragma unroll
    for (int mi = 0; mi < 4; mi++)
      #pragma unroll
      for (int r2 = 0; r2 < 4; r2++) {
        size_t idx = (size_t)(m0 + mi * 16 + fh * 4 + r2) * 256 + col;
        xp[idx] += acc[mi][nj][r2] + bb;
      }
  }
}

// ---------------------------------------------------------------------------
// Attention: seq_len 3, H=8, DH=32, bf16 in/out. 8 sequences per block.
// ---------------------------------------------------------------------------
__global__ __launch_bounds__(256)
void attn(const bf16* __restrict__ qp, const bf16* __restrict__ kp,
          const bf16* __restrict__ vp, bf16* __restrict__ op)
{
  __shared__ __align__(16) u16 qs[6144], ks[6144], vs[6144];
  __shared__ float probs[8][8][9];
  const int tid = threadIdx.x;
  const size_t gbase = (size_t)blockIdx.x * 6144;   // 8 seq * 3 tok * 256
  const uint4* qg = (const uint4*)((const u16*)qp + gbase);
  const uint4* kg = (const uint4*)((const u16*)kp + gbase);
  const uint4* vg = (const uint4*)((const u16*)vp + gbase);
  for (int c = tid; c < 768; c += 256) {
    ((uint4*)qs)[c] = qg[c];
    ((uint4*)ks)[c] = kg[c];
    ((uint4*)vs)[c] = vg[c];
  }
  __syncthreads();
  if (tid < 64) {
    int s = tid >> 3, h = tid & 7;
    int base = s * 768 + h * 32;
    float sc[3][3];
    #pragma unroll
    for (int i = 0; i < 3; i++)
      #pragma unroll
      for (int j = 0; j < 3; j++) {
        float sum = 0.f;
        #pragma unroll
        for (int d = 0; d < 32; d++)
          sum += b2f(qs[base + i * 256 + d]) * b2f(ks[base + j * 256 + d]);
        sc[i][j] = sum * 0.17677669529663687f;   // DH^-0.5
      }
    #pragma unroll
    for (int i = 0; i < 3; i++) {
      float m = fmaxf(sc[i][0], fmaxf(sc[i][1], sc[i][2]));
      float e0 = __expf(sc[i][0] - m);
      float e1 = __expf(sc[i][1] - m);
      float e2 = __expf(sc[i][2] - m);
      float inv = 1.f / (e0 + e1 + e2);
      probs[s][h][i * 3 + 0] = e0 * inv;
      probs[s][h][i * 3 + 1] = e1 * inv;
      probs[s][h][i * 3 + 2] = e2 * inv;
    }
  }
  __syncthreads();
  u16* og = (u16*)op + gbase;
  for (int c = tid; c < 6144; c += 256) {
    int lrow = c >> 8, hd = c & 255;
    int s = lrow / 3, i = lrow - s * 3;
    int h = hd >> 5;
    float p0 = probs[s][h][i * 3 + 0];
    float p1 = probs[s][h][i * 3 + 1];
    float p2 = probs[s][h][i * 3 + 2];
    float o = p0 * b2f(vs[s * 768 + hd])
            + p1 * b2f(vs[s * 768 + 256 + hd])
            + p2 * b2f(vs[s * 768 + 512 + hd]);
    og[c] = f2b(o);
  }
}

// ---------------------------------------------------------------------------
// Final LN + mean over 3 tokens (f32 in, f32 out). 1 wave/seq, 4 seq/block.
// ---------------------------------------------------------------------------
__global__ __launch_bounds__(256)
void ln_final_mean(const float* __restrict__ xp, const float* __restrict__ gp,
                   const float* __restrict__ bp, float* __restrict__ outp)
{
  const int lane = threadIdx.x & 63;
  const int n = blockIdx.x * 4 + (threadIdx.x >> 6);
  float4 gv = *(const float4*)(gp + lane * 4);
  float4 bv4 = *(const float4*)(bp + lane * 4);
  float a0 = 0.f, a1 = 0.f, a2 = 0.f, a3 = 0.f;
  for (int t = 0; t < 3; t++) {
    float4 rv = *(const float4*)(xp + ((size_t)n * 3 + t) * 256 + lane * 4);
    float v0 = rv.x, v1 = rv.y, v2 = rv.z, v3 = rv.w;
    float s = v0 + v1 + v2 + v3;
    float q = v0 * v0 + v1 * v1 + v2 * v2 + v3 * v3;
    #pragma unroll
    for (int m = 32; m > 0; m >>= 1) {
      s += __shfl_xor(s, m, 64);
      q += __shfl_xor(q, m, 64);
    }
    float mean = s * (1.f / 256.f);
    float var = q * (1.f / 256.f) - mean * mean;
    float r = rsqrtf(var + 1e-5f);
    a0 += (v0 - mean) * r * gv.x + bv4.x;
    a1 += (v1 - mean) * r * gv.y + bv4.y;
    a2 += (v2 - mean) * r * gv.z + bv4.z;
    a3 += (v3 - mean) * r * gv.w + bv4.w;
  }
  const float third = 1.f / 3.f;
  float4 outv;
  outv.x = a0 * third;
  outv.y = a1 * third;
  outv.z = a2 * third;
  outv.w = a3 * third;
  *(float4*)(outp + (size_t)n * 256 + lane * 4) = outv;
}

// ---------------------------------------------------------------------------
extern "C" void kernel_launch(void* const* d_in, const int* in_sizes, int n_in,
                              void* d_out, int out_size, void* d_ws, size_t ws_size,
                              hipStream_t stream)
{
  const float* term = (const float*)d_in[0];
  const float* pred = (const float*)d_in[1];
  const float* Wq  = (const float*)d_in[2];
  const float* Wk  = (const float*)d_in[3];
  const float* Wv  = (const float*)d_in[4];
  const float* Wo  = (const float*)d_in[5];
  const float* bq  = (const float*)d_in[6];
  const float* bk  = (const float*)d_in[7];
  const float* bvv = (const float*)d_in[8];
  const float* bo  = (const float*)d_in[9];
  const float* ln1g = (const float*)d_in[10];
  const float* ln1b = (const float*)d_in[11];
  const float* ln2g = (const float*)d_in[12];
  const float* ln2b = (const float*)d_in[13];
  const float* W1  = (const float*)d_in[14];
  const float* b1  = (const float*)d_in[15];
  const float* W2  = (const float*)d_in[16];
  const float* b2  = (const float*)d_in[17];
  const float* lnfg = (const float*)d_in[18];
  const float* lnfb = (const float*)d_in[19];

  // Chunk count from ws_size. Per row: x f32 (1024 B) + q,k,v,o bf16 (2048 B).
  int nch = 128;
  for (int c = 2; c <= 128; c *= 2) {
    size_t Mc_ = (size_t)MROWS / c;
    size_t need = 4ull * 1024 * 1024 + Mc_ * 3072ull;
    if (need <= ws_size) { nch = c; break; }
  }
  const size_t Mc = (size_t)MROWS / nch;     // multiple of 1152

  char* ws = (char*)d_ws;
  bf16* wt   = (bf16*)ws;                    // 1572864 el (3 MB)
  float* bqkv = (float*)(ws + 3145728);      // 1536 f32
  float* x = (float*)(ws + 4194304);         // Mc*256 f32
  bf16* q = (bf16*)(x + Mc * 256);           // q,k,v,o contiguous bf16
  bf16* v_ = q + 2 * Mc * 256;
  bf16* o = q + 3 * Mc * 256;

  prep_weights<<<6145, 256, 0, stream>>>(Wq, Wk, Wv, Wo, W1, W2, bq, bk, bvv, wt, bqkv);

  const long long qkvZ = (long long)(Mc * 256);
  for (int ch = 0; ch < nch; ch++) {
    const int row0 = (int)(ch * Mc);
    build_x<<<(int)(Mc / 4), 256, 0, stream>>>(term, pred, x, row0);
    for (int l = 0; l < 2; l++) {
      const bf16* wl = wt + (size_t)l * 786432;
      qkv_fused<<<(int)(Mc / 64), 256, 0, stream>>>(
          x, ln1g + l * 256, ln1b + l * 256, wl, bqkv + l * 768, q, qkvZ);
      attn<<<(int)(Mc / 24), 256, 0, stream>>>(q, q + Mc * 256, v_, o);
      oproj<<<(int)(Mc / 64), 256, 0, stream>>>(o, wl + 196608, bo + l * 256, x);
      ffn_fused<<<(int)(Mc / 64), 256, 0, stream>>>(
          x, ln2g + l * 256, ln2b + l * 256, wl + 262144, wl + 524288,
          b1 + l * 1024, b2 + l * 256);
    }
    ln_final_mean<<<(int)(Mc / 12), 256, 0, stream>>>(
        x, lnfg, lnfb, (float*)d_out + (size_t)(row0 / 3) * 256);
  }
}

// Round 5
// 1330.318 us; speedup vs baseline: 1.1754x; 1.1754x over previous
//
#include <hip/hip_runtime.h>
#include <hip/hip_bf16.h>
#include <stdint.h>

typedef __hip_bfloat16 bf16;
typedef unsigned short u16;
typedef unsigned int u32;
typedef __bf16 v8bf __attribute__((ext_vector_type(8)));
typedef float v4f __attribute__((ext_vector_type(4)));

// Problem constants
#define NB 16384            // B
#define MROWS 147456        // T*B*3 token rows

__device__ __forceinline__ float b2f(u16 u) {
  union { u32 u; float f; } v; v.u = ((u32)u) << 16; return v.f;
}
__device__ __forceinline__ u16 f2b(float f) {
  union { float f; u32 u; } v; v.f = f;
  u32 u = v.u;
  return (u16)((u + 0x7fffu + ((u >> 16) & 1u)) >> 16);
}
__device__ __forceinline__ void async16(const u16* g, u16* lds) {
  __builtin_amdgcn_global_load_lds((const __attribute__((address_space(1))) void*)g,
                                   (__attribute__((address_space(3))) void*)lds,
                                   16, 0, 0);
}

// ---------------------------------------------------------------------------
// Weight prep: read f32 weights, write transposed bf16 [N][K] (gemm_bt form);
// pack bq/bk/bv contiguously as f32. Per-layer element layout in wt:
// q 0, k 65536, v 131072, o 196608, W1T 262144 (1024x256),
// W2T 524288 (256x1024); layer stride 786432 elements.
// ---------------------------------------------------------------------------
__global__ __launch_bounds__(256)
void prep_weights(const float* Wq, const float* Wk, const float* Wv, const float* Wo,
                  const float* W1, const float* W2,
                  const float* bq, const float* bk, const float* bv,
                  bf16* wt, float* bqkv)
{
  if (blockIdx.x == 6144) {   // bias-pack block
    for (int e = threadIdx.x; e < 1536; e += 256) {
      int l = e / 768;
      int rem = e - l * 768;
      int wsel = rem >> 8;
      int col = rem & 255;
      const float* s = (wsel == 0) ? bq : (wsel == 1) ? bk : bv;
      bqkv[e] = s[l * 256 + col];
    }
    return;
  }
  int gid = blockIdx.x * 256 + threadIdx.x;   // [0, 1572864)
  int layer = (gid >= 786432) ? 1 : 0;
  int r = gid - layer * 786432;
  const float* src; int K, N, e, outoff;
  if (r < 262144) {
    int which = r >> 16;
    e = r & 65535; K = 256; N = 256;
    const float* w = (which == 0) ? Wq : (which == 1) ? Wk : (which == 2) ? Wv : Wo;
    src = w + layer * 65536;
    outoff = layer * 786432 + which * 65536;
  } else if (r < 524288) {
    e = r - 262144; K = 256; N = 1024;
    src = W1 + layer * 262144;
    outoff = layer * 786432 + 262144;
  } else {
    e = r - 524288; K = 1024; N = 256;
    src = W2 + layer * 262144;
    outoff = layer * 786432 + 524288;
  }
  int n = e / K, kk = e - n * K;
  ((u16*)wt)[outoff + e] = f2b(src[kk * N + n]);
}

// ---------------------------------------------------------------------------
// Fused graph-message build + layer-0 LN1: compute x row, write x (f32),
// LayerNorm it, write h (bf16). 1 wave per row, 4 rows per block.
// ---------------------------------------------------------------------------
__global__ __launch_bounds__(256)
void build_ln(const float* __restrict__ T, const float* __restrict__ P,
              const float* __restrict__ gp, const float* __restrict__ bp,
              float* __restrict__ X, bf16* __restrict__ H, int row0)
{
  const int lane = threadIdx.x & 63;
  const int lrow = blockIdx.x * 4 + (threadIdx.x >> 6);
  const int row = row0 + lrow;
  const int d0 = lane * 4;
  int n = row / 3;
  int t = row - n * 3;
  float4 v;
  if (t == 2) {
    v = *(const float4*)(T + (size_t)n * 256 + d0);
  } else {
    int tm = n >> 14, b = n & 16383;
    const int srcT[6] = {1, 2,  0, 2,  1, 0};
    const int srcP[6] = {0, 2,  0, 1,  1, 2};
    const float sg[6] = {-1.f, -1.f,  1.f, -1.f,  1.f, 1.f};
    int idx = tm * 2 + t;
    float4 tv = *(const float4*)(T + ((size_t)(srcT[idx] * NB + b)) * 256 + d0);
    float4 pv = *(const float4*)(P + ((size_t)(srcP[idx] * NB + b)) * 256 + d0);
    float s = sg[idx];
    v.x = tv.x + s * pv.x;
    v.y = tv.y + s * pv.y;
    v.z = tv.z + s * pv.z;
    v.w = tv.w + s * pv.w;
  }
  *(float4*)(X + (size_t)lrow * 256 + d0) = v;
  float s = v.x + v.y + v.z + v.w;
  float q = v.x * v.x + v.y * v.y + v.z * v.z + v.w * v.w;
  #pragma unroll
  for (int m = 32; m > 0; m >>= 1) {
    s += __shfl_xor(s, m, 64);
    q += __shfl_xor(q, m, 64);
  }
  float mean = s * (1.f / 256.f);
  float var = q * (1.f / 256.f) - mean * mean;
  float r = rsqrtf(var + 1e-5f);
  float4 gv = *(const float4*)(gp + d0);
  float4 bv = *(const float4*)(bp + d0);
  ushort4 outv;
  outv.x = f2b((v.x - mean) * r * gv.x + bv.x);
  outv.y = f2b((v.y - mean) * r * gv.y + bv.y);
  outv.z = f2b((v.z - mean) * r * gv.z + bv.z);
  outv.w = f2b((v.w - mean) * r * gv.w + bv.w);
  *(ushort4*)((u16*)H + (size_t)lrow * 256 + d0) = outv;
}

// ---------------------------------------------------------------------------
// LayerNorm over D=256 (f32 in, bf16 out). 1 wave per row, 4 rows per block.
// ---------------------------------------------------------------------------
__global__ __launch_bounds__(256)
void ln_rows(const float* __restrict__ xp, const float* __restrict__ gp,
             const float* __restrict__ bp, bf16* __restrict__ hp)
{
  const int lane = threadIdx.x & 63;
  const int row = blockIdx.x * 4 + (threadIdx.x >> 6);
  float4 rv = *(const float4*)(xp + (size_t)row * 256 + lane * 4);
  float v0 = rv.x, v1 = rv.y, v2 = rv.z, v3 = rv.w;
  float s = v0 + v1 + v2 + v3;
  float q = v0 * v0 + v1 * v1 + v2 * v2 + v3 * v3;
  #pragma unroll
  for (int m = 32; m > 0; m >>= 1) {
    s += __shfl_xor(s, m, 64);
    q += __shfl_xor(q, m, 64);
  }
  float mean = s * (1.f / 256.f);
  float var = q * (1.f / 256.f) - mean * mean;
  float r = rsqrtf(var + 1e-5f);
  float4 gv = *(const float4*)(gp + lane * 4);
  float4 bv = *(const float4*)(bp + lane * 4);
  ushort4 outv;
  outv.x = f2b((v0 - mean) * r * gv.x + bv.x);
  outv.y = f2b((v1 - mean) * r * gv.y + bv.y);
  outv.z = f2b((v2 - mean) * r * gv.z + bv.z);
  outv.w = f2b((v3 - mean) * r * gv.w + bv.w);
  *(ushort4*)((u16*)hp + (size_t)row * 256 + lane * 4) = outv;
}

// ---------------------------------------------------------------------------
// GEMM: C[M,N] = A[M,K] @ Bt[N,K]^T (+bias[col]) (+res) (+relu).
// A,Bt bf16; bias f32; res f32; C bf16 or f32 (OUTF32). fp32 MFMA accumulate.
// 128x128 tile, 4 waves, 4x4 of 16x16x32 per wave, BK=32, double-buffered
// global_load_lds staging (the round-0 harness-verified m97 structure), plus:
//  (a) XCD-sibling grid swizzle: 1D grid; work = (bid&7)*per + bid>>3 with
//      work ordered N/z-siblings-fast -> blocks sharing an A-panel run
//      consecutively on the SAME XCD -> A panel is an L2 hit after the first
//      sibling (round-0 counter evidence: 190 MB FETCH = 8x A re-fetch from
//      HBM because siblings were 288 dispatch slots apart).
//  (b) LDS bank-conflict swizzle: [128][32] tiles alias 8-way (rows 2 apart
//      -> same bank). XOR the 16B slot with (row>>1)&3 on BOTH the
//      global_load_lds source (linear dest) and the ds_read offset; the XOR
//      term is invariant across the i/j fragment strides so it folds into
//      the precomputed per-thread constants (round-0: 4.7M conflict cycles).
// ---------------------------------------------------------------------------
template<int RES, int RELU, int OUTF32>
__global__ __launch_bounds__(256, 4)
void gemm_bt(const bf16* __restrict__ Ap, const bf16* __restrict__ Btp,
             const float* __restrict__ biasp, const float* __restrict__ resp,
             void* __restrict__ Cp, int N, int K,
             int btZ, int biasZ, long long cZ, int nB, int nz)
{
  __shared__ __align__(16) u16 As[2 * 128 * 32];
  __shared__ __align__(16) u16 Bs[2 * 128 * 32];
  // --- XCD-sibling swizzle (gridDim.x % 8 == 0 by construction) ---
  const int per = gridDim.x >> 3;
  const int bid = blockIdx.x;
  const int work = (bid & 7) * per + (bid >> 3);
  const int m = work / nz;
  const int rwk = work - m * nz;
  const int n = rwk % nB;
  const int z = rwk / nB;

  const u16* A = (const u16*)Ap;
  const u16* Bt = (const u16*)Btp + (size_t)z * btZ;
  const float* bias = biasp + (size_t)z * biasZ;
  const int m0 = m * 128;
  const int n0 = n * 128;
  const int tid = threadIdx.x;
  const int w = tid >> 6, lane = tid & 63;
  const int waveM = (w & 1) * 64, waveN = (w >> 1) * 64;

  const int rrow = tid >> 2;                                   // 0..63
  const int kcol = ((tid & 3) ^ ((rrow >> 1) & 3)) * 8;        // swizzled slot
  const u16* pA0 = A + (size_t)(m0 + rrow) * K + kcol;
  const u16* pA1 = A + (size_t)(m0 + rrow + 64) * K + kcol;
  const u16* pB0 = Bt + (size_t)(n0 + rrow) * K + kcol;
  const u16* pB1 = Bt + (size_t)(n0 + rrow + 64) * K + kcol;

  v4f acc[4][4];
  #pragma unroll
  for (int i = 0; i < 4; i++)
    #pragma unroll
    for (int j = 0; j < 4; j++) {
      v4f zz = {0.f, 0.f, 0.f, 0.f};
      acc[i][j] = zz;
    }

  // swizzled read offsets (bytes); XOR term constant across i/j strides
  const int rowA = waveM + (lane & 15);
  const int rdA = rowA * 64 + ((((lane >> 4) ^ ((rowA >> 1) & 3))) << 4);
  const int rowB = waveN + (lane & 15);
  const int rdB = rowB * 64 + ((((lane >> 4) ^ ((rowB >> 1) & 3))) << 4);
  const int nk = K >> 5;

  // preload tile 0 into buffer 0
  async16(pA0, As + w * 512);        async16(pA1, As + 2048 + w * 512);
  async16(pB0, Bs + w * 512);        async16(pB1, Bs + 2048 + w * 512);
  pA0 += 32; pA1 += 32; pB0 += 32; pB1 += 32;

  int cur = 0;
  for (int kt = 0; kt < nk; kt++) {
    __syncthreads();                  // buf[cur] loads complete & visible
    if (kt + 1 < nk) {
      const int nxt = (cur ^ 1) * 4096;
      async16(pA0, As + nxt + w * 512);        async16(pA1, As + nxt + 2048 + w * 512);
      async16(pB0, Bs + nxt + w * 512);        async16(pB1, Bs + nxt + 2048 + w * 512);
      pA0 += 32; pA1 += 32; pB0 += 32; pB1 += 32;
    }
    const char* AsC = (const char*)(As + cur * 4096);
    const char* BsC = (const char*)(Bs + cur * 4096);
    v8bf a[4], b[4];
    #pragma unroll
    for (int i = 0; i < 4; i++)
      a[i] = *(const v8bf*)(AsC + rdA + i * 1024);
    #pragma unroll
    for (int j = 0; j < 4; j++)
      b[j] = *(const v8bf*)(BsC + rdB + j * 1024);
    #pragma unroll
    for (int i = 0; i < 4; i++)
      #pragma unroll
      for (int j = 0; j < 4; j++)
        acc[i][j] = __builtin_amdgcn_mfma_f32_16x16x32_bf16(a[i], b[j], acc[i][j], 0, 0, 0);
    cur ^= 1;
  }

  float bv[4];
  #pragma unroll
  for (int j = 0; j < 4; j++)
    bv[j] = bias[n0 + waveN + j * 16 + (lane & 15)];

  #pragma unroll
  for (int i = 0; i < 4; i++) {
    #pragma unroll
    for (int r = 0; r < 4; r++) {
      int rowg = m0 + waveM + i * 16 + (lane >> 4) * 4 + r;
      size_t rb = (size_t)rowg * N;
      #pragma unroll
      for (int j = 0; j < 4; j++) {
        int colg = n0 + waveN + j * 16 + (lane & 15);
        float vv = acc[i][j][r] + bv[j];
        if (RES) vv += resp[rb + colg];
        if (RELU) vv = fmaxf(vv, 0.f);
        if (OUTF32) ((float*)Cp)[rb + colg] = vv;
        else ((u16*)Cp + (size_t)z * cZ)[rb + colg] = f2b(vv);
      }
    }
  }
}

// ---------------------------------------------------------------------------
// Attention: seq_len 3, H=8, DH=32, bf16 in/out. 8 sequences per block.
// ---------------------------------------------------------------------------
__global__ __launch_bounds__(256)
void attn(const bf16* __restrict__ qp, const bf16* __restrict__ kp,
          const bf16* __restrict__ vp, bf16* __restrict__ op)
{
  __shared__ __align__(16) u16 qs[6144], ks[6144], vs[6144];
  __shared__ float probs[8][8][9];
  const int tid = threadIdx.x;
  const size_t gbase = (size_t)blockIdx.x * 6144;   // 8 seq * 3 tok * 256
  const uint4* qg = (const uint4*)((const u16*)qp + gbase);
  const uint4* kg = (const uint4*)((const u16*)kp + gbase);
  const uint4* vg = (const uint4*)((const u16*)vp + gbase);
  for (int c = tid; c < 768; c += 256) {
    ((uint4*)qs)[c] = qg[c];
    ((uint4*)ks)[c] = kg[c];
    ((uint4*)vs)[c] = vg[c];
  }
  __syncthreads();
  if (tid < 64) {
    int s = tid >> 3, h = tid & 7;
    int base = s * 768 + h * 32;
    float sc[3][3];
    #pragma unroll
    for (int i = 0; i < 3; i++)
      #pragma unroll
      for (int j = 0; j < 3; j++) {
        float sum = 0.f;
        #pragma unroll
        for (int d = 0; d < 32; d++)
          sum += b2f(qs[base + i * 256 + d]) * b2f(ks[base + j * 256 + d]);
        sc[i][j] = sum * 0.17677669529663687f;   // DH^-0.5
      }
    #pragma unroll
    for (int i = 0; i < 3; i++) {
      float m = fmaxf(sc[i][0], fmaxf(sc[i][1], sc[i][2]));
      float e0 = __expf(sc[i][0] - m);
      float e1 = __expf(sc[i][1] - m);
      float e2 = __expf(sc[i][2] - m);
      float inv = 1.f / (e0 + e1 + e2);
      probs[s][h][i * 3 + 0] = e0 * inv;
      probs[s][h][i * 3 + 1] = e1 * inv;
      probs[s][h][i * 3 + 2] = e2 * inv;
    }
  }
  __syncthreads();
  u16* og = (u16*)op + gbase;
  for (int c = tid; c < 6144; c += 256) {
    int lrow = c >> 8, hd = c & 255;
    int s = lrow / 3, i = lrow - s * 3;
    int h = hd >> 5;
    float p0 = probs[s][h][i * 3 + 0];
    float p1 = probs[s][h][i * 3 + 1];
    float p2 = probs[s][h][i * 3 + 2];
    float o = p0 * b2f(vs[s * 768 + hd])
            + p1 * b2f(vs[s * 768 + 256 + hd])
            + p2 * b2f(vs[s * 768 + 512 + hd]);
    og[c] = f2b(o);
  }
}

// ---------------------------------------------------------------------------
// Final LN + mean over 3 tokens (f32 in, f32 out). 1 wave/seq, 4 seq/block.
// ---------------------------------------------------------------------------
__global__ __launch_bounds__(256)
void ln_final_mean(const float* __restrict__ xp, const float* __restrict__ gp,
                   const float* __restrict__ bp, float* __restrict__ outp)
{
  const int lane = threadIdx.x & 63;
  const int n = blockIdx.x * 4 + (threadIdx.x >> 6);
  float4 gv = *(const float4*)(gp + lane * 4);
  float4 bv4 = *(const float4*)(bp + lane * 4);
  float a0 = 0.f, a1 = 0.f, a2 = 0.f, a3 = 0.f;
  for (int t = 0; t < 3; t++) {
    float4 rv = *(const float4*)(xp + ((size_t)n * 3 + t) * 256 + lane * 4);
    float v0 = rv.x, v1 = rv.y, v2 = rv.z, v3 = rv.w;
    float s = v0 + v1 + v2 + v3;
    float q = v0 * v0 + v1 * v1 + v2 * v2 + v3 * v3;
    #pragma unroll
    for (int m = 32; m > 0; m >>= 1) {
      s += __shfl_xor(s, m, 64);
      q += __shfl_xor(q, m, 64);
    }
    float mean = s * (1.f / 256.f);
    float var = q * (1.f / 256.f) - mean * mean;
    float r = rsqrtf(var + 1e-5f);
    a0 += (v0 - mean) * r * gv.x + bv4.x;
    a1 += (v1 - mean) * r * gv.y + bv4.y;
    a2 += (v2 - mean) * r * gv.z + bv4.z;
    a3 += (v3 - mean) * r * gv.w + bv4.w;
  }
  const float third = 1.f / 3.f;
  float4 outv;
  outv.x = a0 * third;
  outv.y = a1 * third;
  outv.z = a2 * third;
  outv.w = a3 * third;
  *(float4*)(outp + (size_t)n * 256 + lane * 4) = outv;
}

// ---------------------------------------------------------------------------
extern "C" void kernel_launch(void* const* d_in, const int* in_sizes, int n_in,
                              void* d_out, int out_size, void* d_ws, size_t ws_size,
                              hipStream_t stream)
{
  const float* term = (const float*)d_in[0];
  const float* pred = (const float*)d_in[1];
  const float* Wq  = (const float*)d_in[2];
  const float* Wk  = (const float*)d_in[3];
  const float* Wv  = (const float*)d_in[4];
  const float* Wo  = (const float*)d_in[5];
  const float* bq  = (const float*)d_in[6];
  const float* bk  = (const float*)d_in[7];
  const float* bvv = (const float*)d_in[8];
  const float* bo  = (const float*)d_in[9];
  const float* ln1g = (const float*)d_in[10];
  const float* ln1b = (const float*)d_in[11];
  const float* ln2g = (const float*)d_in[12];
  const float* ln2b = (const float*)d_in[13];
  const float* W1  = (const float*)d_in[14];
  const float* b1  = (const float*)d_in[15];
  const float* W2  = (const float*)d_in[16];
  const float* b2  = (const float*)d_in[17];
  const float* lnfg = (const float*)d_in[18];
  const float* lnfb = (const float*)d_in[19];

  // Chunk count from ws_size (same selector as the 1594-us baseline -> nch=4).
  // Per row: x f32 (1024 B) + h bf16 (512 B) + q,k,v,o bf16 (2048 B, f aliases).
  int nch = 128;
  for (int c = 1; c <= 128; c *= 2) {
    size_t Mc_ = (size_t)MROWS / c;
    size_t need = 4ull * 1024 * 1024 + Mc_ * 3584ull;
    if (need <= ws_size) { nch = c; break; }
  }
  const size_t Mc = (size_t)MROWS / nch;     // multiple of 1152
  const int mB = (int)(Mc / 128);            // 128-row tiles (288 @ nch=4)

  char* ws = (char*)d_ws;
  bf16* wt   = (bf16*)ws;                    // 1572864 el (3 MB)
  float* bqkv = (float*)(ws + 3145728);      // 1536 f32
  float* x = (float*)(ws + 4194304);         // Mc*256 f32
  bf16* h = (bf16*)(x + Mc * 256);           // Mc*256 bf16
  bf16* q = h + Mc * 256;                    // q,k,v,o contiguous bf16
  bf16* v_ = q + 2 * Mc * 256;
  bf16* o = q + 3 * Mc * 256;
  bf16* f = q;                               // FFN hidden aliases q..o

  prep_weights<<<6145, 256, 0, stream>>>(Wq, Wk, Wv, Wo, W1, W2, bq, bk, bvv, wt, bqkv);

  const long long qkvZ = (long long)(Mc * 256);
  for (int ch = 0; ch < nch; ch++) {
    const int row0 = (int)(ch * Mc);
    // fused: build x rows + layer-0 LN1 -> h
    build_ln<<<(int)(Mc / 4), 256, 0, stream>>>(term, pred, ln1g, ln1b, x, h, row0);
    for (int l = 0; l < 2; l++) {
      const bf16* wl = wt + (size_t)l * 786432;
      if (l > 0)
        ln_rows<<<(int)(Mc / 4), 256, 0, stream>>>(x, ln1g + l * 256, ln1b + l * 256, h);
      gemm_bt<0, 0, 0><<<mB * 6, 256, 0, stream>>>(
          h, wl, bqkv + l * 768, nullptr, q, 256, 256, 65536, 256, qkvZ, 2, 6);
      attn<<<(int)(Mc / 24), 256, 0, stream>>>(q, q + Mc * 256, v_, o);
      gemm_bt<1, 0, 1><<<mB * 2, 256, 0, stream>>>(
          o, wl + 196608, bo + l * 256, x, x, 256, 256, 0, 0, 0, 2, 2);
      ln_rows<<<(int)(Mc / 4), 256, 0, stream>>>(x, ln2g + l * 256, ln2b + l * 256, h);
      gemm_bt<0, 1, 0><<<mB * 8, 256, 0, stream>>>(
          h, wl + 262144, b1 + l * 1024, nullptr, f, 1024, 256, 0, 0, 0, 8, 8);
      gemm_bt<1, 0, 1><<<mB * 2, 256, 0, stream>>>(
          f, wl + 524288, b2 + l * 256, x, x, 256, 1024, 0, 0, 0, 2, 2);
    }
    ln_final_mean<<<(int)(Mc / 12), 256, 0, stream>>>(
        x, lnfg, lnfb, (float*)d_out + (size_t)(row0 / 3) * 256);
  }
}